// Round 8
// baseline (607.299 us; speedup 1.0000x reference)
//
#include <hip/hip_runtime.h>

// LatticeSuperpixel: B=8, C=20, H=W=512, 32x32 seeds, 16x16 cells, 4 levels.
//
// R7 = R6 + 2px/thread k_iter (k_iter2).
//  Budget model: k_iter ~90us x3 dominates (61%); latency/issue-bound
//  (VALUBusy ~30%, 3x over mem+VALU floors). k_iter2: block = 2 cells
//  (16x32 px), thread = 2 px; phase-1 loads float2 issued BEFORE the
//  staging barrier (overlap); seed window (3x4 rows + norms) staged in
//  1 KB LDS (k_final4 pattern); 2-wide softmax; phase 2 = same register
//  tiling, wave (cell,half), contiguous 378-float part store.
//  LDS 22.5 KB -> ~6 blocks/CU (R5 lesson: don't tank occupancy).
//  Kept: zero atomics, (256,4) bounds (R4 spill lesson), XCD swizzle,
//  k_seed_init / k_divz / k_final4 unchanged from R6.
#define NB 8
#define NC 20
#define NH 512
#define NW 512
#define NS 1024           // 32*32 seeds
#define HW (NH * NW)
#define SEEDS_ELEMS (NB * NS * NC)   // 163840
#define SNORM_ELEMS (NB * NS)        // 8192
#define PART_STRIDE 189              // 9 offsets * 21 channels
#define EPSF 1e-8f

static constexpr int DYO[9] = {-1, -1, -1, 0, 0, 0, 1, 1, 1};
static constexpr int DXO[9] = {-1, 0, 1, -1, 0, 1, -1, 0, 1};

__device__ __forceinline__ int clampi(int v, int lo, int hi) {
    return v < lo ? lo : (v > hi ? hi : v);
}

// ---------------------------------------------------------------------------
// Kernel 1: seed init = mean over each 16x16 patch, per channel + seed norm.
// ---------------------------------------------------------------------------
__global__ __launch_bounds__(160) void k_seed_init(const float* __restrict__ x,
                                                   float* __restrict__ seeds,
                                                   float* __restrict__ snorm) {
    __shared__ float sm[NC];
    const int tt = threadIdx.x;           // < 160
    const int cell = blockIdx.x;
    const int b = blockIdx.y;
    const int cy = cell >> 5, cx = cell & 31;
    const int c = tt >> 3, s = tt & 7;

    const float* xb = x + (size_t)b * (NC * HW) + (size_t)c * HW
                        + (size_t)(cy << 4) * NW + (cx << 4);
    float acc = 0.f;
#pragma unroll
    for (int k = 0; k < 8; ++k) {
        const int row = (k << 1) + (s >> 2);
        const int col = (s & 3) << 2;
        const float4 v = *reinterpret_cast<const float4*>(xb + row * NW + col);
        acc += v.x + v.y + v.z + v.w;
    }
    acc += __shfl_xor(acc, 1, 64);
    acc += __shfl_xor(acc, 2, 64);
    acc += __shfl_xor(acc, 4, 64);
    if (s == 0) {
        const float mv = acc * (1.0f / 256.0f);
        seeds[((size_t)(b << 10) + cell) * NC + c] = mv;
        sm[c] = mv;
    }
    __syncthreads();
    if (tt == 0) {
        float n = 0.f;
#pragma unroll
        for (int cc = 0; cc < NC; ++cc) n += sm[cc] * sm[cc];
        snorm[(b << 10) + cell] = n;
    }
}

// ---------------------------------------------------------------------------
// Kernel 2 (NEW): assignment iteration, 2 cells/block, 2 px/thread.
// Prologue: issue own-pixels' 20 float2 loads; stage 12 seed rows + norms.
// Phase 1:  256 thr = 2 px: dist via b128 seed rows (d = |s|^2 - 2 x.s),
//           2-wide softmax -> qs float2.
// Phase 2:  wave w = (cell w>>1, half w&1): 4 strips, register-tiled 21x9;
//           shfl fold; pbuf; contiguous 378-float part store. Zero atomics.
// ---------------------------------------------------------------------------
__global__ __launch_bounds__(256, 4) void k_iter2(const float* __restrict__ x,
                                                  const float* __restrict__ seeds,
                                                  const float* __restrict__ snorm,
                                                  float* __restrict__ part) {
    __shared__ __align__(16) float qs[9][512];      // 18.4 KB
    __shared__ __align__(16) float s_all[3][4][20]; // 0.96 KB
    __shared__ float s_n[3][4];
    __shared__ float pbuf[2][2][192];               // 3.1 KB

    const int t = threadIdx.x;
    const int grp = ((blockIdx.x & 7) << 6) + (blockIdx.x >> 3);  // 0..511
    const int b = blockIdx.y;
    const int cy = grp >> 4, cxg = grp & 15;        // cell-row, 2-cell group
    const int cell0 = (cy << 5) + (cxg << 1);

    const float* xb = x + (size_t)b * (NC * HW) + (size_t)(cy << 4) * NW + (cxg << 5);

    // ---- issue own pixels' loads (overlap with staging below) ----
    const int r = t >> 4, g = t & 15;
    const int q = g >> 3;                           // cell-local 0/1
    const float* xp = xb + r * NW + (g << 1);
    float2 xv[NC];
#pragma unroll
    for (int c = 0; c < NC; ++c)
        xv[c] = *reinterpret_cast<const float2*>(xp + (size_t)c * HW);

    // ---- stage 12 neighbor-seed rows (cols cxg*2-1..+2, rows cy-1..cy+1) ----
    if (t < 120) {
#pragma unroll
        for (int ee = 0; ee < 2; ++ee) {
            const int e = t + ee * 120;             // 0..239
            const int srow = e / 80;
            const int rem = e - srow * 80;
            const int scol = rem / 20;
            const int c = rem - scol * 20;
            const int sy = clampi(cy + srow - 1, 0, 31);
            const int sx = clampi((cxg << 1) + scol - 1, 0, 31);
            s_all[srow][scol][c] =
                seeds[((size_t)((b << 10) + (sy << 5) + sx)) * NC + c];
        }
    }
    if (t < 12) {
        const int srow = t >> 2, scol = t & 3;
        const int sy = clampi(cy + srow - 1, 0, 31);
        const int sx = clampi((cxg << 1) + scol - 1, 0, 31);
        s_n[srow][scol] = snorm[(b << 10) + (sy << 5) + sx];
    }
    __syncthreads();

    // ---- phase 1: distances + 2-wide softmax ----
    float2 ip[9];
#pragma unroll
    for (int o = 0; o < 9; ++o) ip[o] = make_float2(0.f, 0.f);
#pragma unroll
    for (int j = 0; j < 5; ++j) {
#pragma unroll
        for (int o = 0; o < 9; ++o) {
            const float4 s4 = *reinterpret_cast<const float4*>(
                &s_all[DYO[o] + 1][q + DXO[o] + 1][j << 2]);
            const float2 x0 = xv[(j << 2) + 0], x1 = xv[(j << 2) + 1];
            const float2 x2 = xv[(j << 2) + 2], x3 = xv[(j << 2) + 3];
            ip[o].x += x0.x * s4.x + x1.x * s4.y + x2.x * s4.z + x3.x * s4.w;
            ip[o].y += x0.y * s4.x + x1.y * s4.y + x2.y * s4.z + x3.y * s4.w;
        }
    }
#pragma unroll
    for (int o = 0; o < 9; ++o) {
        const float sn = s_n[DYO[o] + 1][q + DXO[o] + 1];
        ip[o].x = sn - 2.0f * ip[o].x;
        ip[o].y = sn - 2.0f * ip[o].y;
    }
    float2 m = ip[0];
#pragma unroll
    for (int o = 1; o < 9; ++o) {
        m.x = fminf(m.x, ip[o].x);
        m.y = fminf(m.y, ip[o].y);
    }
    float2 ws = make_float2(0.f, 0.f);
#pragma unroll
    for (int o = 0; o < 9; ++o) {
        ip[o].x = __expf(m.x - ip[o].x);
        ip[o].y = __expf(m.y - ip[o].y);
        ws.x += ip[o].x;
        ws.y += ip[o].y;
    }
    const float2 inv = make_float2(1.0f / ws.x, 1.0f / ws.y);
#pragma unroll
    for (int o = 0; o < 9; ++o) {
        *reinterpret_cast<float2*>(&qs[o][(r << 5) + (g << 1)]) =
            make_float2(ip[o].x * inv.x, ip[o].y * inv.y);
    }
    __syncthreads();

    // ---- phase 2: wave = (cell, half), register-tiled 21x9 ----
    const int w = t >> 6, tl = t & 63;
    const int cellL = w >> 1, half = w & 1;
    if (tl < 56) {
        const int cg = tl >> 3, s = tl & 7;
        const int r0 = cg * 3;
        float acc[3][9];
#pragma unroll
        for (int j = 0; j < 3; ++j)
#pragma unroll
            for (int o = 0; o < 9; ++o) acc[j][o] = 0.f;

#pragma unroll
        for (int kk = 0; kk < 4; ++kk) {
            const int qd = (((half << 2) + kk) << 3) + s;   // quad id 0..63
            const int row = qd >> 2, qc = qd & 3;
            const float* xr = xb + row * NW + (cellL << 4) + (qc << 2);
            const float4 x0 = *reinterpret_cast<const float4*>(xr + (size_t)(r0 + 0) * HW);
            const float4 x1 = *reinterpret_cast<const float4*>(xr + (size_t)(r0 + 1) * HW);
            float4 x2 = make_float4(1.f, 1.f, 1.f, 1.f);
            if (cg < 6)
                x2 = *reinterpret_cast<const float4*>(xr + (size_t)(r0 + 2) * HW);
#pragma unroll
            for (int o = 0; o < 9; ++o) {
                const float4 q4 = *reinterpret_cast<const float4*>(
                    &qs[o][(row << 5) + (cellL << 4) + (qc << 2)]);
                acc[0][o] += q4.x * x0.x + q4.y * x0.y + q4.z * x0.z + q4.w * x0.w;
                acc[1][o] += q4.x * x1.x + q4.y * x1.y + q4.z * x1.z + q4.w * x1.w;
                acc[2][o] += q4.x * x2.x + q4.y * x2.y + q4.z * x2.z + q4.w * x2.w;
            }
        }
        // fold the 8 strips (s = lane bits 0..2)
#pragma unroll
        for (int j = 0; j < 3; ++j)
#pragma unroll
            for (int o = 0; o < 9; ++o) {
                acc[j][o] += __shfl_xor(acc[j][o], 1, 64);
                acc[j][o] += __shfl_xor(acc[j][o], 2, 64);
                acc[j][o] += __shfl_xor(acc[j][o], 4, 64);
            }
        if (s == 0) {
#pragma unroll
            for (int o = 0; o < 9; ++o)
#pragma unroll
                for (int j = 0; j < 3; ++j)
                    pbuf[cellL][half][o * 21 + r0 + j] = acc[j][o];
        }
    }
    __syncthreads();

    // ---- combine halves + contiguous 378-float store (2 cells adjacent) ----
    const size_t pbase = (size_t)((b << 10) + cell0) * PART_STRIDE;
    for (int i = t; i < 2 * PART_STRIDE; i += 256) {
        const int cl = i / PART_STRIDE, idx = i - cl * PART_STRIDE;
        part[pbase + i] = pbuf[cl][0][idx] + pbuf[cl][1][idx];
    }
}

// ---------------------------------------------------------------------------
// Kernel 3: gather 9-stencil partials -> seeds = num/(den+eps), snorm.
// (identical to R4/R6)
// ---------------------------------------------------------------------------
__global__ __launch_bounds__(192) void k_divz(const float* __restrict__ part,
                                              float* __restrict__ seeds,
                                              float* __restrict__ snorm) {
    __shared__ float den[8];
    __shared__ float sq[8][20];
    const int t = threadIdx.x;
    const int sl = t / 21, c = t - sl * 21;   // valid for t<168
    const int sid = blockIdx.x * 8 + sl;

    float tot = 0.f;
    if (t < 168) {
        const int b = sid >> 10;
        const int s1 = sid & 1023;
        const int sy = s1 >> 5, sx = s1 & 31;

        int cys[3], dys[3], cxs[3], dxs[3];
        cys[0] = sy > 0 ? sy - 1 : 0;   dys[0] = (sy == 0) ? -1 : 1;
        cys[1] = sy;                    dys[1] = 0;
        cys[2] = sy < 31 ? sy + 1 : 31; dys[2] = (sy == 31) ? 1 : -1;
        cxs[0] = sx > 0 ? sx - 1 : 0;   dxs[0] = (sx == 0) ? -1 : 1;
        cxs[1] = sx;                    dxs[1] = 0;
        cxs[2] = sx < 31 ? sx + 1 : 31; dxs[2] = (sx == 31) ? 1 : -1;

#pragma unroll
        for (int jy = 0; jy < 3; ++jy)
#pragma unroll
            for (int jx = 0; jx < 3; ++jx) {
                const int cell = (b << 10) + (cys[jy] << 5) + cxs[jx];
                const int o = (dys[jy] + 1) * 3 + (dxs[jx] + 1);
                tot += part[(size_t)cell * PART_STRIDE + o * 21 + c];
            }
        if (c == 20) den[sl] = tot;
    }
    __syncthreads();
    if (t < 168 && c < 20) {
        const float v = tot / (den[sl] + EPSF);
        seeds[(size_t)sid * NC + c] = v;
        sq[sl][c] = v * v;
    }
    __syncthreads();
    if (t < 8) {
        float n = 0.f;
#pragma unroll
        for (int cc = 0; cc < NC; ++cc) n += sq[t][cc];
        snorm[blockIdx.x * 8 + t] = n;
    }
}

// ---------------------------------------------------------------------------
// Kernel 4: final pass, 4 px/thread (identical to R6's k_final4).
// ---------------------------------------------------------------------------
__global__ __launch_bounds__(256, 4) void k_final4(const float* __restrict__ x,
                                                   const float* __restrict__ seeds,
                                                   const float* __restrict__ snorm,
                                                   float* __restrict__ out) {
    __shared__ __align__(16) float s_all[3][6][20];  // 1.44 KB
    __shared__ float s_n[3][6];

    const int t = threadIdx.x;
    const int grp = ((blockIdx.x & 7) << 5) + (blockIdx.x >> 3);  // 0..255
    const int b = blockIdx.y;
    const int cy = grp >> 3, cxg = grp & 7;   // cell-row, cell-group (4 cells)

    // ---- stage 18 neighbor-seed rows (cols cxg*4-1 .. cxg*4+4, rows cy-1..cy+1)
    if (t < 180) {
#pragma unroll
        for (int ee = 0; ee < 2; ++ee) {
            const int e = t + ee * 180;               // 0..359
            const int srow = e / 120;
            const int rem = e - srow * 120;
            const int scol = rem / 20;
            const int c = rem - scol * 20;
            const int sy = clampi(cy + srow - 1, 0, 31);
            const int sx = clampi((cxg << 2) + scol - 1, 0, 31);
            s_all[srow][scol][c] =
                seeds[((size_t)((b << 10) + (sy << 5) + sx)) * NC + c];
        }
    }
    if (t < 18) {
        const int srow = t / 6, scol = t - srow * 6;
        const int sy = clampi(cy + srow - 1, 0, 31);
        const int sx = clampi((cxg << 2) + scol - 1, 0, 31);
        s_n[srow][scol] = snorm[(b << 10) + (sy << 5) + sx];
    }
    __syncthreads();

    const int r = t >> 4, g = t & 15;
    const int q = g >> 2;                      // cell quadrant 0..3
    const int py = (cy << 4) + r;
    const int px = (cxg << 6) + (g << 2);
    const float* xp = x + (size_t)b * (NC * HW) + (size_t)py * NW + px;

    float4 ip[9];
#pragma unroll
    for (int o = 0; o < 9; ++o) ip[o] = make_float4(0.f, 0.f, 0.f, 0.f);

#pragma unroll
    for (int j = 0; j < 5; ++j) {
        float4 xc[4];
#pragma unroll
        for (int cc = 0; cc < 4; ++cc)
            xc[cc] = *reinterpret_cast<const float4*>(xp + (size_t)((j << 2) + cc) * HW);
#pragma unroll
        for (int o = 0; o < 9; ++o) {
            const float4 s4 = *reinterpret_cast<const float4*>(
                &s_all[DYO[o] + 1][q + DXO[o] + 1][j << 2]);
            ip[o].x += xc[0].x * s4.x + xc[1].x * s4.y + xc[2].x * s4.z + xc[3].x * s4.w;
            ip[o].y += xc[0].y * s4.x + xc[1].y * s4.y + xc[2].y * s4.z + xc[3].y * s4.w;
            ip[o].z += xc[0].z * s4.x + xc[1].z * s4.y + xc[2].z * s4.z + xc[3].z * s4.w;
            ip[o].w += xc[0].w * s4.x + xc[1].w * s4.y + xc[2].w * s4.z + xc[3].w * s4.w;
        }
    }

    // d = sn - 2*ip  (overwrite ip in place)
#pragma unroll
    for (int o = 0; o < 9; ++o) {
        const float sn = s_n[DYO[o] + 1][q + DXO[o] + 1];
        ip[o].x = sn - 2.0f * ip[o].x;
        ip[o].y = sn - 2.0f * ip[o].y;
        ip[o].z = sn - 2.0f * ip[o].z;
        ip[o].w = sn - 2.0f * ip[o].w;
    }
    float4 m = ip[0];
#pragma unroll
    for (int o = 1; o < 9; ++o) {
        m.x = fminf(m.x, ip[o].x);
        m.y = fminf(m.y, ip[o].y);
        m.z = fminf(m.z, ip[o].z);
        m.w = fminf(m.w, ip[o].w);
    }
    float4 ws = make_float4(0.f, 0.f, 0.f, 0.f);
#pragma unroll
    for (int o = 0; o < 9; ++o) {
        ip[o].x = __expf(m.x - ip[o].x);
        ip[o].y = __expf(m.y - ip[o].y);
        ip[o].z = __expf(m.z - ip[o].z);
        ip[o].w = __expf(m.w - ip[o].w);
        ws.x += ip[o].x; ws.y += ip[o].y; ws.z += ip[o].z; ws.w += ip[o].w;
    }
    const float4 inv = make_float4(1.0f / ws.x, 1.0f / ws.y, 1.0f / ws.z, 1.0f / ws.w);
#pragma unroll
    for (int o = 0; o < 9; ++o) {
        const float4 v = make_float4(ip[o].x * inv.x, ip[o].y * inv.y,
                                     ip[o].z * inv.z, ip[o].w * inv.w);
        *reinterpret_cast<float4*>(
            &out[(((size_t)b * 9 + o) * NH + py) * NW + px]) = v;
    }
}

// ---------------------------------------------------------------------------
extern "C" void kernel_launch(void* const* d_in, const int* in_sizes, int n_in,
                              void* d_out, int out_size, void* d_ws, size_t ws_size,
                              hipStream_t stream) {
    const float* x = (const float*)d_in[0];
    float* out = (float*)d_out;

    float* seeds = (float*)d_ws;                    // 163840 floats
    float* snorm = seeds + SEEDS_ELEMS;             // 8192 floats
    float* part  = snorm + SNORM_ELEMS;             // 1548288 floats

    const dim3 gseed(NS, NB);
    k_seed_init<<<gseed, 160, 0, stream>>>(x, seeds, snorm);

    for (int it = 0; it < 3; ++it) {
        k_iter2<<<dim3(512, NB), 256, 0, stream>>>(x, seeds, snorm, part);
        k_divz<<<NB * NS / 8, 192, 0, stream>>>(part, seeds, snorm);
    }
    k_final4<<<dim3(256, NB), 256, 0, stream>>>(x, seeds, snorm, out);
}

// Round 9
// 592.441 us; speedup vs baseline: 1.0251x; 1.0251x over previous
//
#include <hip/hip_runtime.h>

// LatticeSuperpixel: B=8, C=20, H=W=512, 32x32 seeds, 16x16 cells, 4 levels.
//
// R8 = R7 with the spill fixed.
//  R7 post-mortem: xv[20] (float2, 40 dwords) loaded BEFORE the staging
//  barrier and consumed after -> held live across barrier -> scratch spill
//  (WRITE_SIZE 157 MB = 1.05M thr x 40 floats; FETCH +64 MB re-reads).
//  Fix (k_final4's proven pattern): stage seeds first, barrier, then STREAM
//  channels in groups of 4 inside the distance loop (peak live ~30 regs).
//  Kept from R7: 2 cells/block, 2px/thread, 2-wide softmax, 4-wave phase 2
//  (wave = (cell, half)), contiguous 378-float part store, zero atomics,
//  (256,4) bounds, XCD swizzle; k_seed_init / k_divz / k_final4 from R6.
#define NB 8
#define NC 20
#define NH 512
#define NW 512
#define NS 1024           // 32*32 seeds
#define HW (NH * NW)
#define SEEDS_ELEMS (NB * NS * NC)   // 163840
#define SNORM_ELEMS (NB * NS)        // 8192
#define PART_STRIDE 189              // 9 offsets * 21 channels
#define EPSF 1e-8f

static constexpr int DYO[9] = {-1, -1, -1, 0, 0, 0, 1, 1, 1};
static constexpr int DXO[9] = {-1, 0, 1, -1, 0, 1, -1, 0, 1};

__device__ __forceinline__ int clampi(int v, int lo, int hi) {
    return v < lo ? lo : (v > hi ? hi : v);
}

// ---------------------------------------------------------------------------
// Kernel 1: seed init = mean over each 16x16 patch, per channel + seed norm.
// ---------------------------------------------------------------------------
__global__ __launch_bounds__(160) void k_seed_init(const float* __restrict__ x,
                                                   float* __restrict__ seeds,
                                                   float* __restrict__ snorm) {
    __shared__ float sm[NC];
    const int tt = threadIdx.x;           // < 160
    const int cell = blockIdx.x;
    const int b = blockIdx.y;
    const int cy = cell >> 5, cx = cell & 31;
    const int c = tt >> 3, s = tt & 7;

    const float* xb = x + (size_t)b * (NC * HW) + (size_t)c * HW
                        + (size_t)(cy << 4) * NW + (cx << 4);
    float acc = 0.f;
#pragma unroll
    for (int k = 0; k < 8; ++k) {
        const int row = (k << 1) + (s >> 2);
        const int col = (s & 3) << 2;
        const float4 v = *reinterpret_cast<const float4*>(xb + row * NW + col);
        acc += v.x + v.y + v.z + v.w;
    }
    acc += __shfl_xor(acc, 1, 64);
    acc += __shfl_xor(acc, 2, 64);
    acc += __shfl_xor(acc, 4, 64);
    if (s == 0) {
        const float mv = acc * (1.0f / 256.0f);
        seeds[((size_t)(b << 10) + cell) * NC + c] = mv;
        sm[c] = mv;
    }
    __syncthreads();
    if (tt == 0) {
        float n = 0.f;
#pragma unroll
        for (int cc = 0; cc < NC; ++cc) n += sm[cc] * sm[cc];
        snorm[(b << 10) + cell] = n;
    }
}

// ---------------------------------------------------------------------------
// Kernel 2: assignment iteration, 2 cells/block, 2 px/thread, STREAMED ch.
// Stage 12 seed rows + norms -> barrier -> phase 1 streams channels in
// groups of 4 (load xc[4] float2, accumulate ip[9]); 2-wide softmax -> qs.
// Phase 2: wave = (cell, half): register-tiled 21x9 from global x (L1/L2-hot)
// + qs LDS; shfl fold; pbuf; contiguous 378-float part store. Zero atomics.
// ---------------------------------------------------------------------------
__global__ __launch_bounds__(256, 4) void k_iter2(const float* __restrict__ x,
                                                  const float* __restrict__ seeds,
                                                  const float* __restrict__ snorm,
                                                  float* __restrict__ part) {
    __shared__ __align__(16) float qs[9][512];      // 18.4 KB
    __shared__ __align__(16) float s_all[3][4][20]; // 0.96 KB
    __shared__ float s_n[3][4];
    __shared__ float pbuf[2][2][192];               // 3.1 KB

    const int t = threadIdx.x;
    const int grp = ((blockIdx.x & 7) << 6) + (blockIdx.x >> 3);  // 0..511
    const int b = blockIdx.y;
    const int cy = grp >> 4, cxg = grp & 15;        // cell-row, 2-cell group
    const int cell0 = (cy << 5) + (cxg << 1);

    const float* xb = x + (size_t)b * (NC * HW) + (size_t)(cy << 4) * NW + (cxg << 5);

    // ---- stage 12 neighbor-seed rows (cols cxg*2-1..+2, rows cy-1..cy+1) ----
    if (t < 120) {
#pragma unroll
        for (int ee = 0; ee < 2; ++ee) {
            const int e = t + ee * 120;             // 0..239
            const int srow = e / 80;
            const int rem = e - srow * 80;
            const int scol = rem / 20;
            const int c = rem - scol * 20;
            const int sy = clampi(cy + srow - 1, 0, 31);
            const int sx = clampi((cxg << 1) + scol - 1, 0, 31);
            s_all[srow][scol][c] =
                seeds[((size_t)((b << 10) + (sy << 5) + sx)) * NC + c];
        }
    }
    if (t < 12) {
        const int srow = t >> 2, scol = t & 3;
        const int sy = clampi(cy + srow - 1, 0, 31);
        const int sx = clampi((cxg << 1) + scol - 1, 0, 31);
        s_n[srow][scol] = snorm[(b << 10) + (sy << 5) + sx];
    }
    __syncthreads();

    // ---- phase 1: streamed distances + 2-wide softmax ----
    const int r = t >> 4, g = t & 15;
    const int q = g >> 3;                           // cell-local 0/1
    const float* xp = xb + r * NW + (g << 1);

    float2 ip[9];
#pragma unroll
    for (int o = 0; o < 9; ++o) ip[o] = make_float2(0.f, 0.f);
#pragma unroll
    for (int j = 0; j < 5; ++j) {
        float2 xc[4];
#pragma unroll
        for (int cc = 0; cc < 4; ++cc)
            xc[cc] = *reinterpret_cast<const float2*>(xp + (size_t)((j << 2) + cc) * HW);
#pragma unroll
        for (int o = 0; o < 9; ++o) {
            const float4 s4 = *reinterpret_cast<const float4*>(
                &s_all[DYO[o] + 1][q + DXO[o] + 1][j << 2]);
            ip[o].x += xc[0].x * s4.x + xc[1].x * s4.y + xc[2].x * s4.z + xc[3].x * s4.w;
            ip[o].y += xc[0].y * s4.x + xc[1].y * s4.y + xc[2].y * s4.z + xc[3].y * s4.w;
        }
    }
#pragma unroll
    for (int o = 0; o < 9; ++o) {
        const float sn = s_n[DYO[o] + 1][q + DXO[o] + 1];
        ip[o].x = sn - 2.0f * ip[o].x;
        ip[o].y = sn - 2.0f * ip[o].y;
    }
    float2 m = ip[0];
#pragma unroll
    for (int o = 1; o < 9; ++o) {
        m.x = fminf(m.x, ip[o].x);
        m.y = fminf(m.y, ip[o].y);
    }
    float2 ws = make_float2(0.f, 0.f);
#pragma unroll
    for (int o = 0; o < 9; ++o) {
        ip[o].x = __expf(m.x - ip[o].x);
        ip[o].y = __expf(m.y - ip[o].y);
        ws.x += ip[o].x;
        ws.y += ip[o].y;
    }
    const float2 inv = make_float2(1.0f / ws.x, 1.0f / ws.y);
#pragma unroll
    for (int o = 0; o < 9; ++o) {
        *reinterpret_cast<float2*>(&qs[o][(r << 5) + (g << 1)]) =
            make_float2(ip[o].x * inv.x, ip[o].y * inv.y);
    }
    __syncthreads();

    // ---- phase 2: wave = (cell, half), register-tiled 21x9 ----
    const int w = t >> 6, tl = t & 63;
    const int cellL = w >> 1, half = w & 1;
    if (tl < 56) {
        const int cg = tl >> 3, s = tl & 7;
        const int r0 = cg * 3;
        float acc[3][9];
#pragma unroll
        for (int j = 0; j < 3; ++j)
#pragma unroll
            for (int o = 0; o < 9; ++o) acc[j][o] = 0.f;

#pragma unroll
        for (int kk = 0; kk < 4; ++kk) {
            const int qd = (((half << 2) + kk) << 3) + s;   // quad id 0..63
            const int row = qd >> 2, qc = qd & 3;
            const float* xr = xb + row * NW + (cellL << 4) + (qc << 2);
            const float4 x0 = *reinterpret_cast<const float4*>(xr + (size_t)(r0 + 0) * HW);
            const float4 x1 = *reinterpret_cast<const float4*>(xr + (size_t)(r0 + 1) * HW);
            float4 x2 = make_float4(1.f, 1.f, 1.f, 1.f);
            if (cg < 6)
                x2 = *reinterpret_cast<const float4*>(xr + (size_t)(r0 + 2) * HW);
#pragma unroll
            for (int o = 0; o < 9; ++o) {
                const float4 q4 = *reinterpret_cast<const float4*>(
                    &qs[o][(row << 5) + (cellL << 4) + (qc << 2)]);
                acc[0][o] += q4.x * x0.x + q4.y * x0.y + q4.z * x0.z + q4.w * x0.w;
                acc[1][o] += q4.x * x1.x + q4.y * x1.y + q4.z * x1.z + q4.w * x1.w;
                acc[2][o] += q4.x * x2.x + q4.y * x2.y + q4.z * x2.z + q4.w * x2.w;
            }
        }
        // fold the 8 strips (s = lane bits 0..2)
#pragma unroll
        for (int j = 0; j < 3; ++j)
#pragma unroll
            for (int o = 0; o < 9; ++o) {
                acc[j][o] += __shfl_xor(acc[j][o], 1, 64);
                acc[j][o] += __shfl_xor(acc[j][o], 2, 64);
                acc[j][o] += __shfl_xor(acc[j][o], 4, 64);
            }
        if (s == 0) {
#pragma unroll
            for (int o = 0; o < 9; ++o)
#pragma unroll
                for (int j = 0; j < 3; ++j)
                    pbuf[cellL][half][o * 21 + r0 + j] = acc[j][o];
        }
    }
    __syncthreads();

    // ---- combine halves + contiguous 378-float store (2 cells adjacent) ----
    const size_t pbase = (size_t)((b << 10) + cell0) * PART_STRIDE;
    for (int i = t; i < 2 * PART_STRIDE; i += 256) {
        const int cl = i / PART_STRIDE, idx = i - cl * PART_STRIDE;
        part[pbase + i] = pbuf[cl][0][idx] + pbuf[cl][1][idx];
    }
}

// ---------------------------------------------------------------------------
// Kernel 3: gather 9-stencil partials -> seeds = num/(den+eps), snorm.
// (identical to R4/R6)
// ---------------------------------------------------------------------------
__global__ __launch_bounds__(192) void k_divz(const float* __restrict__ part,
                                              float* __restrict__ seeds,
                                              float* __restrict__ snorm) {
    __shared__ float den[8];
    __shared__ float sq[8][20];
    const int t = threadIdx.x;
    const int sl = t / 21, c = t - sl * 21;   // valid for t<168
    const int sid = blockIdx.x * 8 + sl;

    float tot = 0.f;
    if (t < 168) {
        const int b = sid >> 10;
        const int s1 = sid & 1023;
        const int sy = s1 >> 5, sx = s1 & 31;

        int cys[3], dys[3], cxs[3], dxs[3];
        cys[0] = sy > 0 ? sy - 1 : 0;   dys[0] = (sy == 0) ? -1 : 1;
        cys[1] = sy;                    dys[1] = 0;
        cys[2] = sy < 31 ? sy + 1 : 31; dys[2] = (sy == 31) ? 1 : -1;
        cxs[0] = sx > 0 ? sx - 1 : 0;   dxs[0] = (sx == 0) ? -1 : 1;
        cxs[1] = sx;                    dxs[1] = 0;
        cxs[2] = sx < 31 ? sx + 1 : 31; dxs[2] = (sx == 31) ? 1 : -1;

#pragma unroll
        for (int jy = 0; jy < 3; ++jy)
#pragma unroll
            for (int jx = 0; jx < 3; ++jx) {
                const int cell = (b << 10) + (cys[jy] << 5) + cxs[jx];
                const int o = (dys[jy] + 1) * 3 + (dxs[jx] + 1);
                tot += part[(size_t)cell * PART_STRIDE + o * 21 + c];
            }
        if (c == 20) den[sl] = tot;
    }
    __syncthreads();
    if (t < 168 && c < 20) {
        const float v = tot / (den[sl] + EPSF);
        seeds[(size_t)sid * NC + c] = v;
        sq[sl][c] = v * v;
    }
    __syncthreads();
    if (t < 8) {
        float n = 0.f;
#pragma unroll
        for (int cc = 0; cc < NC; ++cc) n += sq[t][cc];
        snorm[blockIdx.x * 8 + t] = n;
    }
}

// ---------------------------------------------------------------------------
// Kernel 4: final pass, 4 px/thread (identical to R6's k_final4).
// ---------------------------------------------------------------------------
__global__ __launch_bounds__(256, 4) void k_final4(const float* __restrict__ x,
                                                   const float* __restrict__ seeds,
                                                   const float* __restrict__ snorm,
                                                   float* __restrict__ out) {
    __shared__ __align__(16) float s_all[3][6][20];  // 1.44 KB
    __shared__ float s_n[3][6];

    const int t = threadIdx.x;
    const int grp = ((blockIdx.x & 7) << 5) + (blockIdx.x >> 3);  // 0..255
    const int b = blockIdx.y;
    const int cy = grp >> 3, cxg = grp & 7;   // cell-row, cell-group (4 cells)

    // ---- stage 18 neighbor-seed rows (cols cxg*4-1 .. cxg*4+4, rows cy-1..cy+1)
    if (t < 180) {
#pragma unroll
        for (int ee = 0; ee < 2; ++ee) {
            const int e = t + ee * 180;               // 0..359
            const int srow = e / 120;
            const int rem = e - srow * 120;
            const int scol = rem / 20;
            const int c = rem - scol * 20;
            const int sy = clampi(cy + srow - 1, 0, 31);
            const int sx = clampi((cxg << 2) + scol - 1, 0, 31);
            s_all[srow][scol][c] =
                seeds[((size_t)((b << 10) + (sy << 5) + sx)) * NC + c];
        }
    }
    if (t < 18) {
        const int srow = t / 6, scol = t - srow * 6;
        const int sy = clampi(cy + srow - 1, 0, 31);
        const int sx = clampi((cxg << 2) + scol - 1, 0, 31);
        s_n[srow][scol] = snorm[(b << 10) + (sy << 5) + sx];
    }
    __syncthreads();

    const int r = t >> 4, g = t & 15;
    const int q = g >> 2;                      // cell quadrant 0..3
    const int py = (cy << 4) + r;
    const int px = (cxg << 6) + (g << 2);
    const float* xp = x + (size_t)b * (NC * HW) + (size_t)py * NW + px;

    float4 ip[9];
#pragma unroll
    for (int o = 0; o < 9; ++o) ip[o] = make_float4(0.f, 0.f, 0.f, 0.f);

#pragma unroll
    for (int j = 0; j < 5; ++j) {
        float4 xc[4];
#pragma unroll
        for (int cc = 0; cc < 4; ++cc)
            xc[cc] = *reinterpret_cast<const float4*>(xp + (size_t)((j << 2) + cc) * HW);
#pragma unroll
        for (int o = 0; o < 9; ++o) {
            const float4 s4 = *reinterpret_cast<const float4*>(
                &s_all[DYO[o] + 1][q + DXO[o] + 1][j << 2]);
            ip[o].x += xc[0].x * s4.x + xc[1].x * s4.y + xc[2].x * s4.z + xc[3].x * s4.w;
            ip[o].y += xc[0].y * s4.x + xc[1].y * s4.y + xc[2].y * s4.z + xc[3].y * s4.w;
            ip[o].z += xc[0].z * s4.x + xc[1].z * s4.y + xc[2].z * s4.z + xc[3].z * s4.w;
            ip[o].w += xc[0].w * s4.x + xc[1].w * s4.y + xc[2].w * s4.z + xc[3].w * s4.w;
        }
    }

    // d = sn - 2*ip  (overwrite ip in place)
#pragma unroll
    for (int o = 0; o < 9; ++o) {
        const float sn = s_n[DYO[o] + 1][q + DXO[o] + 1];
        ip[o].x = sn - 2.0f * ip[o].x;
        ip[o].y = sn - 2.0f * ip[o].y;
        ip[o].z = sn - 2.0f * ip[o].z;
        ip[o].w = sn - 2.0f * ip[o].w;
    }
    float4 m = ip[0];
#pragma unroll
    for (int o = 1; o < 9; ++o) {
        m.x = fminf(m.x, ip[o].x);
        m.y = fminf(m.y, ip[o].y);
        m.z = fminf(m.z, ip[o].z);
        m.w = fminf(m.w, ip[o].w);
    }
    float4 ws = make_float4(0.f, 0.f, 0.f, 0.f);
#pragma unroll
    for (int o = 0; o < 9; ++o) {
        ip[o].x = __expf(m.x - ip[o].x);
        ip[o].y = __expf(m.y - ip[o].y);
        ip[o].z = __expf(m.z - ip[o].z);
        ip[o].w = __expf(m.w - ip[o].w);
        ws.x += ip[o].x; ws.y += ip[o].y; ws.z += ip[o].z; ws.w += ip[o].w;
    }
    const float4 inv = make_float4(1.0f / ws.x, 1.0f / ws.y, 1.0f / ws.z, 1.0f / ws.w);
#pragma unroll
    for (int o = 0; o < 9; ++o) {
        const float4 v = make_float4(ip[o].x * inv.x, ip[o].y * inv.y,
                                     ip[o].z * inv.z, ip[o].w * inv.w);
        *reinterpret_cast<float4*>(
            &out[(((size_t)b * 9 + o) * NH + py) * NW + px]) = v;
    }
}

// ---------------------------------------------------------------------------
extern "C" void kernel_launch(void* const* d_in, const int* in_sizes, int n_in,
                              void* d_out, int out_size, void* d_ws, size_t ws_size,
                              hipStream_t stream) {
    const float* x = (const float*)d_in[0];
    float* out = (float*)d_out;

    float* seeds = (float*)d_ws;                    // 163840 floats
    float* snorm = seeds + SEEDS_ELEMS;             // 8192 floats
    float* part  = snorm + SNORM_ELEMS;             // 1548288 floats

    const dim3 gseed(NS, NB);
    k_seed_init<<<gseed, 160, 0, stream>>>(x, seeds, snorm);

    for (int it = 0; it < 3; ++it) {
        k_iter2<<<dim3(512, NB), 256, 0, stream>>>(x, seeds, snorm, part);
        k_divz<<<NB * NS / 8, 192, 0, stream>>>(part, seeds, snorm);
    }
    k_final4<<<dim3(256, NB), 256, 0, stream>>>(x, seeds, snorm, out);
}